// Round 3
// baseline (159.442 us; speedup 1.0000x reference)
//
#include <hip/hip_runtime.h>

// Canvas geometry from the reference.
#define H 6144
#define W 6144
#define BLOCK 384          // one row = 384 threads x 16 px; 6 waves/block
#define GRID  1536         // 4 rows per block (6144 / 1536); ~5-6 blocks/CU
#define GSTRIDE 1536       // y-distance (px) between a thread's 4-px groups

typedef float v4f __attribute__((ext_vector_type(4)));

__global__ __launch_bounds__(BLOCK) void
LineRaster2d_kernel(const float* __restrict__ p0g,
                    const float* __restrict__ p1g,
                    float* __restrict__ out) {
    // Uniform setup (scalar loads / SALU): endpoints in pixel coords.
    const float p0x = p0g[0] * (float)H;
    const float p0y = p0g[1] * (float)W;
    const float dx  = p1g[0] * (float)H - p0x;
    const float dy  = p1g[1] * (float)W - p0y;
    const float inv_len_sq = __builtin_amdgcn_rcpf(dx * dx + dy * dy);

    const int   t       = threadIdx.x;
    const float py_base = (float)(t * 4) - p0y;   // y offset of group 0

    // Each block iteration handles one full row; px is wave-uniform (SALU).
    for (int r = blockIdx.x; r < H; r += GRID) {
        const float px    = (float)r - p0x;
        const float px_dx = px * dx;
        v4f* row4 = reinterpret_cast<v4f*>(out + (size_t)r * W) + t;

        // Conservative reject: one point-to-segment test per 4-px group at
        // the group center (y0+1.5). Farthest pixel is 1.5 away and dist is
        // 1-Lipschitz, so dist_center >= 2.5 => all 4 pixels >= 1 => zero.
        // Test squared dist against 9.0 (dist 3.0) for rounding margin.
        float d2[4];
#pragma unroll
        for (int j = 0; j < 4; ++j) {
            const float pyc = py_base + (float)(j * GSTRIDE) + 1.5f;
            float tc = (px_dx + pyc * dy) * inv_len_sq;
            tc = fminf(fmaxf(tc, 0.0f), 1.0f);
            const float ex = px  - tc * dx;
            const float ey = pyc - tc * dy;
            d2[j] = ex * ex + ey * ey;
        }
        const float d2min = fminf(fminf(d2[0], d2[1]), fminf(d2[2], d2[3]));

        if (d2min < 9.0f) {            // ~3% of waves -> execz-skipped usually
#pragma unroll
            for (int j = 0; j < 4; ++j) {
                v4f v = (v4f)0.0f;
#pragma unroll
                for (int i = 0; i < 4; ++i) {
                    const float py = py_base + (float)(j * GSTRIDE + i);
                    float tt = (px_dx + py * dy) * inv_len_sq;
                    tt = fminf(fmaxf(tt, 0.0f), 1.0f);
                    const float ex = px - tt * dx;
                    const float ey = py - tt * dy;
                    const float dist = __builtin_amdgcn_sqrtf(ex * ex + ey * ey);
                    v[i] = (dist < 1.0f) ? (1.0f - dist) : 0.0f;
                }
                __builtin_nontemporal_store(v, row4 + j * (GSTRIDE / 4));
            }
        } else {
            const v4f z = (v4f)0.0f;
#pragma unroll
            for (int j = 0; j < 4; ++j)
                __builtin_nontemporal_store(z, row4 + j * (GSTRIDE / 4));
        }
    }
}

extern "C" void kernel_launch(void* const* d_in, const int* in_sizes, int n_in,
                              void* d_out, int out_size, void* d_ws, size_t ws_size,
                              hipStream_t stream) {
    const float* p0 = (const float*)d_in[0];
    const float* p1 = (const float*)d_in[1];
    float* out = (float*)d_out;

    LineRaster2d_kernel<<<GRID, BLOCK, 0, stream>>>(p0, p1, out);
}

// Round 4
// 151.249 us; speedup vs baseline: 1.0542x; 1.0542x over previous
//
#include <hip/hip_runtime.h>

// Canvas geometry from the reference.
#define H 6144
#define W 6144
#define BLOCK 256
// 8 minor-axis candidates per major row; 6176 major slots (6144 + margin,
// rounded so grid*BLOCK/8 is integral).
#define MAJOR_SLOTS 6176
#define GRID ((MAJOR_SLOTS * 8) / BLOCK)   // 193 blocks

// Sparse pass: write only pixels inside the width-2 capsule around the
// segment. d_out has already been zeroed by hipMemsetAsync on the same
// stream. Coverage bound (see journal): at major coord m, every pixel with
// dist < 1 has minor coord in (center(m)-2, center(m)+2) where
// center(m) = p0n + clamp((m-p0m)/dm, 0, 1)*dn and |dn| <= |dm|.
// We scan [floor(center)-3, floor(center)+4] -- 8 candidates, >=1px margin.
__global__ __launch_bounds__(BLOCK) void
LineRaster2d_sparse(const float* __restrict__ p0g,
                    const float* __restrict__ p1g,
                    float* __restrict__ out) {
    const int i     = blockIdx.x * BLOCK + threadIdx.x;
    const int m_idx = i >> 3;
    const int off   = i & 7;

    // Uniform setup (scalar loads / SALU): endpoints in pixel coords.
    const float p0x = p0g[0] * (float)H;
    const float p0y = p0g[1] * (float)W;
    const float p1x = p1g[0] * (float)H;
    const float p1y = p1g[1] * (float)W;
    const float dx  = p1x - p0x;
    const float dy  = p1y - p0y;
    const float inv_len_sq = __builtin_amdgcn_rcpf(dx * dx + dy * dy);

    // Major axis = dominant direction (wave-uniform branch).
    const bool xmajor = fabsf(dx) >= fabsf(dy);
    const float pm0 = xmajor ? p0x : p0y;
    const float pm1 = xmajor ? p1x : p1y;
    const float pn0 = xmajor ? p0y : p0x;
    const float dm  = pm1 - pm0;
    const float dn  = xmajor ? dy : dx;
    const float inv_dm = (dm != 0.0f) ? __builtin_amdgcn_rcpf(dm) : 0.0f;

    const int m = (int)floorf(fminf(pm0, pm1)) - 2 + m_idx;
    if ((unsigned)m >= (unsigned)H) return;   // H == W: bound works both ways

    // Spine crossing at this major coord, clamped to the segment.
    float ct = ((float)m - pm0) * inv_dm;
    ct = fminf(fmaxf(ct, 0.0f), 1.0f);
    const float center = pn0 + ct * dn;

    const int n = (int)floorf(center) - 3 + off;
    if ((unsigned)n >= (unsigned)W) return;

    const int x = xmajor ? m : n;
    const int y = xmajor ? n : m;

    // Exact same per-pixel formula as the dense kernel (absmax-validated).
    const float px = (float)x - p0x;
    const float py = (float)y - p0y;
    float t = (px * dx + py * dy) * inv_len_sq;
    t = fminf(fmaxf(t, 0.0f), 1.0f);
    const float ex = px - t * dx;
    const float ey = py - t * dy;
    const float dist = __builtin_amdgcn_sqrtf(ex * ex + ey * ey);

    if (dist < 1.0f) out[(size_t)x * W + y] = 1.0f - dist;
}

extern "C" void kernel_launch(void* const* d_in, const int* in_sizes, int n_in,
                              void* d_out, int out_size, void* d_ws, size_t ws_size,
                              hipStream_t stream) {
    const float* p0 = (const float*)d_in[0];
    const float* p1 = (const float*)d_in[1];
    float* out = (float*)d_out;

    // Zero the canvas via the runtime's optimized fill path (~6.6 TB/s
    // measured on this device), then overlay the sparse capsule.
    hipMemsetAsync(out, 0, (size_t)out_size * sizeof(float), stream);
    LineRaster2d_sparse<<<GRID, BLOCK, 0, stream>>>(p0, p1, out);
}